// Round 10
// baseline (415.507 us; speedup 1.0000x reference)
//
#include <hip/hip_runtime.h>
#include <hip/hip_bf16.h>
#include <stdint.h>

#define BATCH   16384
#define D_IN    2000
#define HID     100
#define OUT_DIM 2
#define BN_EPS_VAL 1e-5f

#define BK      32
#define BN_PAD  128
#define KT      63                      // ceil(2000/32)
#define W1Q_ELEMS (KT * BN_PAD * BK)    // 258048
#define G1_REPS 4                       // instrumentation: gemm1 visible in top-5

typedef float f32x4 __attribute__((ext_vector_type(4)));
typedef short bf16x8 __attribute__((ext_vector_type(8)));

// ---------------- workspace layout (bytes) ----------------
// [0, 4096): float F[] scalars (zeroed by memset each launch)
//   F[0..4] absmaxes; F[16..116) b1_int; F[116..316) w2_int;
//   F[320..420) mu; F[420..520) rstd; u32 S1@F+520; u32 S2@F+620;
//   F[920..922) b2_int; F[922] b_s2
// [4096, +516096): ushort w1q[63][128][32]   (bf16 bits, K-tile-major)
// [1MB): float h1[16384][100]
// [8MB): u8 q2[16384][100]
// [10MB): float out2[16384][2]
#define WS_W1Q_OFF 4096
#define WS_H1_OFF  (1u << 20)
#define WS_Q2_OFF  (8u << 20)
#define WS_O2_OFF  (10u << 20)

__device__ __forceinline__ unsigned short f2bf(float q) {
    return (unsigned short)(__float_as_uint(q) >> 16);   // exact for small ints
}

__device__ __forceinline__ void block_atomic_maxf(float v, float* dst) {
#pragma unroll
    for (int off = 32; off > 0; off >>= 1)
        v = fmaxf(v, __shfl_xor(v, off, 64));
    __shared__ float sm[8];
    const int w = threadIdx.x >> 6;
    if ((threadIdx.x & 63) == 0) sm[w] = v;
    __syncthreads();
    if (threadIdx.x == 0) {
        const int nw = (blockDim.x + 63) >> 6;
        float m = sm[0];
        for (int i = 1; i < nw; ++i) m = fmaxf(m, sm[i]);
        atomicMax((unsigned int*)dst, __float_as_uint(m)); // all values >= 0
    }
}

// ---------------- K0: absmax of sig / W1 / W2 ----------------
__global__ __launch_bounds__(256)
void k_absmax(const float* __restrict__ sig, const float* __restrict__ W1,
              const float* __restrict__ W2, float* __restrict__ F) {
    float m = 0.0f;
    const int b = blockIdx.x;
    if (b < 2048) {
        const float4* p = (const float4*)sig;
        const int n4 = BATCH * D_IN / 4;
        for (int i = b * 256 + threadIdx.x; i < n4; i += 2048 * 256) {
            float4 v = p[i];
            m = fmaxf(m, fmaxf(fmaxf(fabsf(v.x), fabsf(v.y)),
                               fmaxf(fabsf(v.z), fabsf(v.w))));
        }
        block_atomic_maxf(m, &F[0]);
    } else if (b < 2064) {
        const float4* p = (const float4*)W1;
        const int n4 = HID * D_IN / 4;
        for (int i = (b - 2048) * 256 + threadIdx.x; i < n4; i += 16 * 256) {
            float4 v = p[i];
            m = fmaxf(m, fmaxf(fmaxf(fabsf(v.x), fabsf(v.y)),
                               fmaxf(fabsf(v.z), fabsf(v.w))));
        }
        block_atomic_maxf(m, &F[1]);
    } else {
        if (threadIdx.x < OUT_DIM * HID) m = fabsf(W2[threadIdx.x]);
        block_atomic_maxf(m, &F[2]);
    }
}

// ---------------- K1: quantize W1 (tiled bf16), b1, W2 ----------------
__global__ __launch_bounds__(256)
void k_prep(const float* __restrict__ W1, const float* __restrict__ b1,
            const float* __restrict__ W2, float* __restrict__ F,
            unsigned short* __restrict__ w1q) {
    const int tid = blockIdx.x * 256 + threadIdx.x;
    const float ws1 = F[1];
    if (tid < W1Q_ELEMS) {
        const int kt = tid >> 12;
        const int r  = tid & 4095;
        const int n  = r >> 5;
        const int kk = r & 31;
        const int k  = kt * 32 + kk;
        float q = 0.0f;
        if (n < HID && k < D_IN) {
            q = rintf(W1[n * D_IN + k] / ws1);
            q = fminf(fmaxf(q, -2.0f), 1.0f);
        }
        w1q[tid] = f2bf(q);
    } else if (tid < W1Q_ELEMS + HID) {
        const int h = tid - W1Q_ELEMS;
        const float bs = ws1 * (F[0] / 15.0f);
        F[16 + h] = fminf(fmaxf(rintf(b1[h] / bs), -2.0f), 1.0f);
    } else if (tid < W1Q_ELEMS + HID + OUT_DIM * HID) {
        const int j = tid - (W1Q_ELEMS + HID);
        F[116 + j] = fminf(fmaxf(rintf(W2[j] / F[2]), -2.0f), 1.0f);
    }
}

// ---------------- K2: GEMM1 — barrier-free, in-register quantize, x G1_REPS ----
// 512 blocks x 256 thr (4 waves). Block owns 32 rows (2 row-groups); wave ks
// owns contiguous kt chunk {0-15,16-31,32-47,48-62}. Per kt: load+quantize two
// A-frags straight from sig (L3-resident; per row 4 lanes x 32B = 128B
// contiguous), 7 B-frags direct from L2 (reused for both row-groups), 14 MFMA.
// No LDS/barriers in the loop. Exact-integer partials -> order-free LDS reduce.
__global__ __launch_bounds__(256)
void k_gemm1(const float* __restrict__ sig, const unsigned short* __restrict__ w1q,
             float* __restrict__ F, float* __restrict__ h1) {
    __shared__ float red[3][32][113];
    const int t    = threadIdx.x;
    const int lane = t & 63;
    const int ks   = t >> 6;
    const float s1  = F[0] / 15.0f;
    const float bs1 = F[1] * s1;
    const int m0 = blockIdx.x * 32;
    const int fr = lane & 15;
    const int g8 = (lane >> 4) * 8;

    const float* aptr0 = sig + (size_t)(m0 + fr) * D_IN;
    const float* aptr1 = sig + (size_t)(m0 + 16 + fr) * D_IN;

    const int kt0 = ks * 16;
    const int kt1 = (ks == 3) ? KT : kt0 + 16;
    const int rl  = (lane >> 4) * 4;        // C/D row base: (lane>>4)*4 + r

#pragma unroll 1
    for (int rep = 0; rep < G1_REPS; ++rep) {   // idempotent instrumentation
        f32x4 accA[7] = {}, accB[7] = {};

        for (int kt = kt0; kt < kt1; ++kt) {
            const int k0 = kt * BK + g8;
            float eA[8], eB[8];
            if (k0 + 8 <= D_IN) {
                const float4 a0 = *(const float4*)(aptr0 + k0);
                const float4 a1 = *(const float4*)(aptr0 + k0 + 4);
                const float4 b0 = *(const float4*)(aptr1 + k0);
                const float4 b1v = *(const float4*)(aptr1 + k0 + 4);
                eA[0]=a0.x; eA[1]=a0.y; eA[2]=a0.z; eA[3]=a0.w;
                eA[4]=a1.x; eA[5]=a1.y; eA[6]=a1.z; eA[7]=a1.w;
                eB[0]=b0.x; eB[1]=b0.y; eB[2]=b0.z; eB[3]=b0.w;
                eB[4]=b1v.x; eB[5]=b1v.y; eB[6]=b1v.z; eB[7]=b1v.w;
            } else {
#pragma unroll
                for (int j = 0; j < 8; ++j) { eA[j] = 0.0f; eB[j] = 0.0f; }
            }
            union { bf16x8 v; unsigned short s[8]; } A, B;
#pragma unroll
            for (int j = 0; j < 8; ++j) {
                A.s[j] = f2bf(fminf(fmaxf(rintf(eA[j] / s1), -16.0f), 15.0f));
                B.s[j] = f2bf(fminf(fmaxf(rintf(eB[j] / s1), -16.0f), 15.0f));
            }
            const unsigned short* bbase = w1q + ((size_t)kt * BN_PAD + fr) * BK + g8;
#pragma unroll
            for (int tt = 0; tt < 7; ++tt) {
                const bf16x8 bf = *(const bf16x8*)(bbase + tt * 16 * BK);
                accA[tt] = __builtin_amdgcn_mfma_f32_16x16x32_bf16(A.v, bf, accA[tt], 0, 0, 0);
                accB[tt] = __builtin_amdgcn_mfma_f32_16x16x32_bf16(B.v, bf, accB[tt], 0, 0, 0);
            }
        }

        if (ks != 0) {
#pragma unroll
            for (int tt = 0; tt < 7; ++tt)
#pragma unroll
                for (int r = 0; r < 4; ++r) {
                    red[ks - 1][rl + r][tt * 16 + fr]      = accA[tt][r];
                    red[ks - 1][16 + rl + r][tt * 16 + fr] = accB[tt][r];
                }
        }
        __syncthreads();

        float lmax = 0.0f;
        if (ks == 0) {
#pragma unroll
            for (int tt = 0; tt < 7; ++tt) {
                const int n = tt * 16 + fr;     // C/D col = lane&15
                if (n < HID) {
                    const float bi = F[16 + n];
#pragma unroll
                    for (int r = 0; r < 4; ++r) {   // exact-int adds: order-free
                        float hA = (accA[tt][r] + red[0][rl + r][n] + red[1][rl + r][n]
                                    + red[2][rl + r][n] + bi) * bs1;
                        float hB = (accB[tt][r] + red[0][16 + rl + r][n] + red[1][16 + rl + r][n]
                                    + red[2][16 + rl + r][n] + bi) * bs1;
                        hA = fmaxf(hA, 0.0f);
                        hB = fmaxf(hB, 0.0f);
                        h1[(size_t)(m0 + rl + r) * HID + n]      = hA;
                        h1[(size_t)(m0 + 16 + rl + r) * HID + n] = hB;
                        lmax = fmaxf(lmax, fmaxf(hA, hB));
                    }
                }
            }
        }
        block_atomic_maxf(lmax, &F[3]);
        __syncthreads();                    // WAR: next rep rewrites red
    }
}

// ---------------- K3: quantize h1 -> int8 codes + exact column sums ----------------
__global__ __launch_bounds__(256)
void k_quant_h(const float* __restrict__ h1, unsigned char* __restrict__ q2,
               const float* __restrict__ F, unsigned int* __restrict__ S1,
               unsigned int* __restrict__ S2) {
    __shared__ unsigned int ls1[HID], ls2[HID];
    if (threadIdx.x < HID) { ls1[threadIdx.x] = 0u; ls2[threadIdx.x] = 0u; }
    __syncthreads();
    const float s2 = F[3] / 127.0f;
    const int base = blockIdx.x * 6400;          // 64 rows x 100 cols
#pragma unroll 5
    for (int it = 0; it < 25; ++it) {
        const int idx = base + it * 256 + threadIdx.x;
        const float h = h1[idx];                 // >= 0
        const int q = (int)fminf(rintf(h / s2), 127.0f);
        q2[idx] = (unsigned char)q;
        const int c = idx % HID;
        atomicAdd(&ls1[c], (unsigned int)q);
        atomicAdd(&ls2[c], (unsigned int)(q * q));
    }
    __syncthreads();
    if (threadIdx.x < HID) {
        atomicAdd(&S1[threadIdx.x], ls1[threadIdx.x]);
        atomicAdd(&S2[threadIdx.x], ls2[threadIdx.x]);
    }
}

// ---------------- K4: BN stats + b2 quant ----------------
__global__ void k_bnprep(const float* __restrict__ b2, float* __restrict__ F,
                         const unsigned int* __restrict__ S1,
                         const unsigned int* __restrict__ S2) {
    const int t = threadIdx.x;
    const float s2  = F[3] / 127.0f;
    const float bs2 = F[2] * s2;
    if (t < HID) {
        const double sd   = (double)s2;
        const double mean = sd * ((double)S1[t] / 16384.0);
        const double ex2  = sd * sd * ((double)S2[t] / 16384.0);
        const double var  = ex2 - mean * mean;
        const float vpe   = (float)var + BN_EPS_VAL;
        F[320 + t] = (float)mean;
        F[420 + t] = (float)(1.0 / sqrt((double)vpe));
    }
    if (t < OUT_DIM) F[920 + t] = fminf(fmaxf(rintf(b2[t] / bs2), -2.0f), 1.0f);
    if (t == 64) F[922] = bs2;
}

// ---------------- K5: BN + GEMM2 (N=2, VALU) + relu + absmax ----------------
__global__ __launch_bounds__(256)
void k_gemm2(const unsigned char* __restrict__ q2, float* __restrict__ F,
             const float* __restrict__ gamma, const float* __restrict__ beta,
             float* __restrict__ out2) {
    __shared__ float sw[2 * HID], smu[HID], sr[HID], sg[HID], sb[HID];
    __shared__ float ssc[4];
    const int t = threadIdx.x;
    if (t < 2 * HID) sw[t] = F[116 + t];
    if (t < HID) { smu[t] = F[320 + t]; sr[t] = F[420 + t]; sg[t] = gamma[t]; sb[t] = beta[t]; }
    if (t == 200) ssc[0] = F[3] / 127.0f;
    if (t == 201) ssc[1] = F[922];
    if (t == 202) ssc[2] = F[920];
    if (t == 203) ssc[3] = F[921];
    __syncthreads();
    const int row = blockIdx.x * 256 + t;
    const unsigned int* rp = (const unsigned int*)(q2 + (size_t)row * HID);
    const float s2 = ssc[0];
    float a0 = 0.0f, a1 = 0.0f;
#pragma unroll
    for (int j = 0; j < 25; ++j) {
        const unsigned int u = rp[j];
#pragma unroll
        for (int bb = 0; bb < 4; ++bb) {
            const int h = j * 4 + bb;
            const float q = (float)((u >> (8 * bb)) & 255u);
            const float x2v = q * s2;
            const float xb  = fmaf((x2v - smu[h]) * sr[h], sg[h], sb[h]);
            const float xi  = xb / s2;
            a0 = fmaf(xi, sw[h], a0);
            a1 = fmaf(xi, sw[HID + h], a1);
        }
    }
    const float o0 = fmaxf((a0 + ssc[2]) * ssc[1], 0.0f);
    const float o1 = fmaxf((a1 + ssc[3]) * ssc[1], 0.0f);
    out2[row * 2 + 0] = o0;
    out2[row * 2 + 1] = o1;
    block_atomic_maxf(fmaxf(o0, o1), &F[4]);
}

// ---------------- K6: final 8-bit quant_act ----------------
__global__ __launch_bounds__(256)
void k_final(const float* __restrict__ out2, const float* __restrict__ F,
             float* __restrict__ out) {
    const int i = blockIdx.x * 256 + threadIdx.x;     // 8192 float4s
    const float s3 = F[4] / 127.0f;
    float4 v = ((const float4*)out2)[i];
    float4 r;
    r.x = fminf(fmaxf(rintf(v.x / s3), -128.f), 127.f) * s3;
    r.y = fminf(fmaxf(rintf(v.y / s3), -128.f), 127.f) * s3;
    r.z = fminf(fmaxf(rintf(v.z / s3), -128.f), 127.f) * s3;
    r.w = fminf(fmaxf(rintf(v.w / s3), -128.f), 127.f) * s3;
    ((float4*)out)[i] = r;
}

extern "C" void kernel_launch(void* const* d_in, const int* in_sizes, int n_in,
                              void* d_out, int out_size, void* d_ws, size_t ws_size,
                              hipStream_t stream) {
    const float* sig   = (const float*)d_in[0];
    const float* W1    = (const float*)d_in[1];
    const float* b1    = (const float*)d_in[2];
    const float* W2    = (const float*)d_in[3];
    const float* b2    = (const float*)d_in[4];
    const float* gamma = (const float*)d_in[5];
    const float* beta  = (const float*)d_in[6];

    float* F = (float*)d_ws;
    unsigned short* w1q = (unsigned short*)((char*)d_ws + WS_W1Q_OFF);
    float* h1           = (float*)((char*)d_ws + WS_H1_OFF);
    unsigned char* q2   = (unsigned char*)((char*)d_ws + WS_Q2_OFF);
    float* o2           = (float*)((char*)d_ws + WS_O2_OFF);
    unsigned int* S1    = (unsigned int*)(F + 520);
    unsigned int* S2    = (unsigned int*)(F + 620);

    hipMemsetAsync(d_ws, 0, 4096, stream);
    k_absmax <<<2065, 256, 0, stream>>>(sig, W1, W2, F);
    k_prep   <<<1010, 256, 0, stream>>>(W1, b1, W2, F, w1q);
    k_gemm1  <<<512,  256, 0, stream>>>(sig, w1q, F, h1);
    k_quant_h<<<256,  256, 0, stream>>>(h1, q2, F, S1, S2);
    k_bnprep <<<1,    128, 0, stream>>>(b2, F, S1, S2);
    k_gemm2  <<<64,   256, 0, stream>>>(q2, F, gamma, beta, o2);
    k_final  <<<32,   256, 0, stream>>>(o2, F, (float*)d_out);
}